// Round 11
// baseline (47.437 us; speedup 1.0000x reference)
//
#include <hip/hip_runtime.h>
#include <hip/hip_bf16.h>

#define BATCH 4096
#define NCLS  10000
#define CPAD  10240   // 80 * 128
#define FDIM  512
#define MAXL  32

typedef float f32x4 __attribute__((ext_vector_type(4)));
typedef int   ix4   __attribute__((ext_vector_type(4)));
typedef int   ix8   __attribute__((ext_vector_type(8)));

__device__ static inline void gld_lds16(const void* g, void* l) {
    __builtin_amdgcn_global_load_lds(
        (const __attribute__((address_space(1))) void*)g,
        (__attribute__((address_space(3))) void*)l, 16, 0, 0);
}

// fp4 e2m1 encode: nearest of {0,.5,1,1.5,2,3,4,6}, sign<<3 | code.
__device__ static inline unsigned int fp4e(float v) {
    unsigned int s = (__float_as_uint(v) >> 31) << 3;
    float a = fabsf(v);
    unsigned int c;
    if      (a < 1.25f) c = (a < 0.75f) ? (a < 0.25f ? 0u : 1u) : 2u;
    else if (a < 2.5f)  c = (a < 1.75f) ? 3u : 4u;
    else                c = (a < 3.5f) ? 5u : (a < 5.f ? 6u : 7u);
    return s | c;
}

// Tile-major lane-linear fp4 layout for mfma_scale_16x16x128 (FMT=4):
// supertile = 16 rows x 512 k = 4KB, [kt2 = k>>7] selects a 1KB subtile.
// Within a 1KB (16 rows x 128 k) subtile, MFMA lane l = (row&15) + 16*((k>>5)&3)
// owns its 32 k-contiguous elements as 16 lane-linear bytes:
//   byte = ((k>>5)&3)*256 + (row&15)*16 + ((k&31)>>1), nibble = k&1.
// A 128-row x 512-k operand panel = 8 contiguous supertiles = 32KB.
__device__ static inline int pdst4(int row, int k) {
    return (row >> 4) * 4096 + (k >> 7) * 1024
         + ((k >> 5) & 3) * 256 + (row & 15) * 16 + ((k & 31) >> 1);
}

// ---------------- merged prep: x->fp4+norms (bid<BATCH) | center update->fp4 (else) ----------------
__global__ void prep_all(const float* __restrict__ x, const int* __restrict__ labels,
                         const float* __restrict__ centers, const float* __restrict__ lr,
                         unsigned char* __restrict__ xq, float* __restrict__ xnorm,
                         unsigned char* __restrict__ cq, float* __restrict__ cnorm,
                         float* __restrict__ out) {
    const int bid = blockIdx.x, t = threadIdx.x;
    __shared__ float red[4];
    if (bid < BATCH) {
        if (bid == 0 && t == 0) out[0] = 0.f;
        int i = bid;
        float2 v = *(const float2*)&x[(size_t)i * FDIM + 2 * t];
        xq[pdst4(i, 2 * t)] = (unsigned char)(fp4e(v.x) | (fp4e(v.y) << 4));
        float s = v.x * v.x + v.y * v.y;
#pragma unroll
        for (int m = 1; m < 64; m <<= 1) s += __shfl_xor(s, m);
        if ((t & 63) == 0) red[t >> 6] = s;
        __syncthreads();
        if (t == 0) xnorm[i] = red[0] + red[1] + red[2] + red[3];
        return;
    }
    int j = bid - BATCH;
    if (j >= NCLS) {  // padding rows: zero fp4, huge norm -> rcp(1+d) ~ 1e-30 (self-masking)
        cq[pdst4(j, 2 * t)] = 0;
        if (t == 0) cnorm[j] = 1e30f;
        return;
    }
    __shared__ int nmatch;
    __shared__ int idxs[MAXL];
    if (t == 0) nmatch = 0;
    __syncthreads();
    {   // vectorized label scan: 4 independent int4 loads (one round-trip, not 16)
        const int4* l4 = (const int4*)labels;
        int4 a0 = l4[t], a1 = l4[t + 256], a2 = l4[t + 512], a3 = l4[t + 768];
#define CHK(V, B) { \
        if (V.x == j) { int p = atomicAdd(&nmatch, 1); if (p < MAXL) idxs[p] = (B); } \
        if (V.y == j) { int p = atomicAdd(&nmatch, 1); if (p < MAXL) idxs[p] = (B) + 1; } \
        if (V.z == j) { int p = atomicAdd(&nmatch, 1); if (p < MAXL) idxs[p] = (B) + 2; } \
        if (V.w == j) { int p = atomicAdd(&nmatch, 1); if (p < MAXL) idxs[p] = (B) + 3; } }
        CHK(a0, 4 * t) CHK(a1, 4 * (t + 256)) CHK(a2, 4 * (t + 512)) CHK(a3, 4 * (t + 768))
#undef CHK
    }
    __syncthreads();
    int cfull = nmatch;
    int c = cfull > MAXL ? MAXL : cfull;
    if (t == 0 && c > 1) {  // sort tiny list -> deterministic fp add order
        for (int a = 1; a < c; ++a) {
            int v = idxs[a]; int b = a - 1;
            while (b >= 0 && idxs[b] > v) { idxs[b + 1] = idxs[b]; --b; }
            idxs[b + 1] = v;
        }
    }
    __syncthreads();
    float cf  = (float)cfull;
    float lr0 = lr[0];
    float inv = 1.f / (1.f + cf);
    float c0 = centers[(size_t)j * FDIM + 2 * t];
    float c1 = centers[(size_t)j * FDIM + 2 * t + 1];
    float sx0 = 0.f, sx1 = 0.f;
    for (int q = 0; q < c; ++q) {
        const float* xr = &x[(size_t)idxs[q] * FDIM + 2 * t];
        sx0 += xr[0]; sx1 += xr[1];
    }
    float n0 = c0 - lr0 * (cf * c0 - sx0) * inv;
    float n1 = c1 - lr0 * (cf * c1 - sx1) * inv;
    cq[pdst4(j, 2 * t)] = (unsigned char)(fp4e(n0) | (fp4e(n1) << 4));
    float cn2 = n0 * n0 + n1 * n1;
#pragma unroll
    for (int m = 1; m < 64; m <<= 1) cn2 += __shfl_xor(cn2, m);
    if ((t & 63) == 0) red[t >> 6] = cn2;
    __syncthreads();
    if (t == 0) cnorm[j] = red[0] + red[1] + red[2] + red[3];
}

// ---------------- pairwise: MX-fp4, 128x128, SINGLE-SHOT K (whole K=512 in LDS) ----------------
// No double buffer, no per-step barriers: stage 64KB once, one vmcnt(0)+barrier,
// then 64 MFMAs/wave back-to-back (compiler interleaves ds_read_b128 freely).
__global__ void __launch_bounds__(256, 2)
pairwise(const unsigned char* __restrict__ xq, const unsigned char* __restrict__ cq,
         const float* __restrict__ xnorm, const float* __restrict__ cnorm,
         const int* __restrict__ labels, float* __restrict__ row_part) {
    __shared__ unsigned char Als[32768];
    __shared__ unsigned char Bls[32768];
    const int tid = threadIdx.x;
    const int w = tid >> 6, lane = tid & 63;
    const int lr16 = lane & 15, lhi = lane >> 4;
    // XCD-chunked bijective swizzle: 2560 = 8 XCD * 320 (10 by-panels x 32 bx each)
    const int bid = blockIdx.x;
    const int swz = (bid & 7) * 320 + (bid >> 3);
    const int bx = swz & 31, by = swz >> 5;
    const int m_blk = bx * 128, n_blk = by * 128;
    const int mq = (w >> 1) * 64, nq = (w & 1) * 64;

    f32x4 acc[4][4];
#pragma unroll
    for (int a = 0; a < 4; ++a)
#pragma unroll
        for (int b = 0; b < 4; ++b) acc[a][b] = (f32x4)0.f;

    // stage the full 32KB A-panel + 32KB B-panel (contiguous in tile-major layout);
    // identity copy: thread t, chunk q -> byte q*4096 + t*16. 16 loads/thread.
    const unsigned char* gA = xq + (size_t)(m_blk >> 4) * 4096 + tid * 16;
    const unsigned char* gB = cq + (size_t)(n_blk >> 4) * 4096 + tid * 16;
#pragma unroll
    for (int q = 0; q < 8; ++q) {
        gld_lds16(gA + q * 4096, &Als[q * 4096 + tid * 16]);
        gld_lds16(gB + q * 4096, &Bls[q * 4096 + tid * 16]);
    }
    asm volatile("s_waitcnt vmcnt(0)" ::: "memory");
    __builtin_amdgcn_s_barrier();

    // barrier-free K loop: 4 chunks x 16 MFMA. Frag = ONE lane-linear ds_read_b128
    // (lane's 32 fp4 = 16B; regs v[0:3], upper half dup'd). SWAPPED operands:
    // mfma(B,A) puts m on lanes (col=lane&15), n on regs. FMT=4 (fp4).
#pragma unroll
    for (int kt2 = 0; kt2 < 4; ++kt2) {
        ix8 af[4], bg[4];
#pragma unroll
        for (int mi = 0; mi < 4; ++mi) {
            ix4 lo = *(const ix4*)&Als[((mq >> 4) + mi) * 4096 + kt2 * 1024 + lane * 16];
            af[mi] = __builtin_shufflevector(lo, lo, 0, 1, 2, 3, 0, 1, 2, 3);
        }
#pragma unroll
        for (int ni = 0; ni < 4; ++ni) {
            ix4 lo = *(const ix4*)&Bls[((nq >> 4) + ni) * 4096 + kt2 * 1024 + lane * 16];
            bg[ni] = __builtin_shufflevector(lo, lo, 0, 1, 2, 3, 0, 1, 2, 3);
        }
        __builtin_amdgcn_s_setprio(1);
#pragma unroll
        for (int mi = 0; mi < 4; ++mi)
#pragma unroll
            for (int ni = 0; ni < 4; ++ni)
                acc[mi][ni] = __builtin_amdgcn_mfma_scale_f32_16x16x128_f8f6f4(
                    bg[ni], af[mi], acc[mi][ni], 4, 4, 0, 0x7F7F7F7F, 0, 0x7F7F7F7F);
        __builtin_amdgcn_s_setprio(0);
    }

    // epilogue (swapped layout): lane owns m = mq+mi*16+lr16; its 16 regs per mi are
    // n = nq+ni*16+lhi*4+r. Local 16-sum of rcp, then 2 shfl (xor16,32) across lhi.
    float rsum[4];
#pragma unroll
    for (int mi = 0; mi < 4; ++mi) {
        int m_g = m_blk + mq + mi * 16 + lr16;
        float xn1 = 1.f + xnorm[m_g];
        int lab = labels[m_g];
        float s = 0.f;
#pragma unroll
        for (int ni = 0; ni < 4; ++ni) {
#pragma unroll
            for (int r = 0; r < 4; ++r) {
                int n_g = n_blk + nq + ni * 16 + lhi * 4 + r;
                float d1 = xn1 + cnorm[n_g] - 2.f * acc[mi][ni][r];
                float rc = __builtin_amdgcn_rcpf(d1);
                s += (n_g != lab) ? rc : 0.f;
            }
        }
        s += __shfl_xor(s, 16);
        s += __shfl_xor(s, 32);
        rsum[mi] = s;
    }
    __syncthreads();                     // all LDS frag reads done before reuse
    float* spart = (float*)&Als[0];
    if ((w & 1) && lhi == 0) {           // waves with nq=64 deposit partials
#pragma unroll
        for (int mi = 0; mi < 4; ++mi)
            spart[mq + mi * 16 + lr16] = rsum[mi];
    }
    __syncthreads();
    if (!(w & 1) && lhi == 0) {          // waves with nq=0 combine + store
        float* rp = row_part + (size_t)by * BATCH + m_blk;
#pragma unroll
        for (int mi = 0; mi < 4; ++mi) {
            int ml = mq + mi * 16 + lr16;
            rp[ml] = rsum[mi] + spart[ml];
        }
    }
}

// ---------------- finalize: sum 80 parts per row, clamp, mean ----------------
__global__ void finalize(const float* __restrict__ row_part, float* __restrict__ out) {
    int i = blockIdx.x * 256 + threadIdx.x;   // 4096 rows
    float s = 0.f;
    for (int p = 0; p < CPAD / 128; ++p) s += row_part[(size_t)p * BATCH + i];
    float dist = fminf(fmaxf(s, 1e-12f), 1e12f);
    float v = dist * (1.f / BATCH);
#pragma unroll
    for (int m = 1; m < 64; m <<= 1) v += __shfl_xor(v, m);
    __shared__ float red[4];
    if ((threadIdx.x & 63) == 0) red[threadIdx.x >> 6] = v;
    __syncthreads();
    if (threadIdx.x == 0) atomicAdd(out, red[0] + red[1] + red[2] + red[3]);
}

extern "C" void kernel_launch(void* const* d_in, const int* in_sizes, int n_in,
                              void* d_out, int out_size, void* d_ws, size_t ws_size,
                              hipStream_t stream) {
    const float* x       = (const float*)d_in[0];
    const int*   labels  = (const int*)d_in[1];
    const float* centers = (const float*)d_in[2];
    const float* lr      = (const float*)d_in[3];
    float* out = (float*)d_out;

    char* ws = (char*)d_ws;
    size_t off = 0;
    unsigned char* cq = (unsigned char*)(ws + off); off += (size_t)CPAD * FDIM / 2;   // 2.62 MB
    unsigned char* xq = (unsigned char*)(ws + off); off += (size_t)BATCH * FDIM / 2;  // 1.05 MB
    float* cnorm    = (float*)(ws + off); off += (size_t)CPAD * 4;
    float* xnorm    = (float*)(ws + off); off += (size_t)BATCH * 4;
    float* row_part = (float*)(ws + off); off += (size_t)(CPAD / 128) * BATCH * 4;    // 1.31 MB

    prep_all<<<BATCH + CPAD, 256, 0, stream>>>(x, labels, centers, lr,
                                               xq, xnorm, cq, cnorm, out);
    pairwise<<<(BATCH / 128) * (CPAD / 128), 256, 0, stream>>>(xq, cq, xnorm, cnorm, labels, row_part);
    finalize<<<BATCH / 256, 256, 0, stream>>>(row_part, out);
}

// Round 12
// 43.597 us; speedup vs baseline: 1.0881x; 1.0881x over previous
//
#include <hip/hip_runtime.h>
#include <hip/hip_bf16.h>

#define BATCH 4096
#define NCLS  10000
#define CPAD  10240   // 80 * 128 = 16 * 640
#define FDIM  512
#define MAXL  32

typedef float f32x4 __attribute__((ext_vector_type(4)));
typedef int   ix4   __attribute__((ext_vector_type(4)));
typedef int   ix8   __attribute__((ext_vector_type(8)));

__device__ static inline void gld_lds16(const void* g, void* l) {
    __builtin_amdgcn_global_load_lds(
        (const __attribute__((address_space(1))) void*)g,
        (__attribute__((address_space(3))) void*)l, 16, 0, 0);
}

// fp4 e2m1 encode: nearest of {0,.5,1,1.5,2,3,4,6}, sign<<3 | code.
__device__ static inline unsigned int fp4e(float v) {
    unsigned int s = (__float_as_uint(v) >> 31) << 3;
    float a = fabsf(v);
    unsigned int c;
    if      (a < 1.25f) c = (a < 0.75f) ? (a < 0.25f ? 0u : 1u) : 2u;
    else if (a < 2.5f)  c = (a < 1.75f) ? 3u : 4u;
    else                c = (a < 3.5f) ? 5u : (a < 5.f ? 6u : 7u);
    return s | c;
}

// Tile-major lane-linear fp4 layout (mfma_scale_16x16x128, FMT=4):
// supertile = 16 rows x 512 k = 4KB; [k>>7] selects 1KB subtile; inside, MFMA
// lane l = (row&15)+16*((k>>5)&3) owns 32 k-contiguous elems as 16 bytes:
//   byte = ((k>>5)&3)*256 + (row&15)*16 + ((k&31)>>1), nibble = k&1.
__device__ static inline int pdst4(int row, int k) {
    return (row >> 4) * 4096 + (k >> 7) * 1024
         + ((k >> 5) & 3) * 256 + (row & 15) * 16 + ((k & 31) >> 1);
}

// ---------------- merged prep: x->fp4+norms (bid<BATCH) | center update->fp4 (else) ----------------
__global__ void prep_all(const float* __restrict__ x, const int* __restrict__ labels,
                         const float* __restrict__ centers, const float* __restrict__ lr,
                         unsigned char* __restrict__ xq, float* __restrict__ xnorm,
                         unsigned char* __restrict__ cq, float* __restrict__ cnorm,
                         float* __restrict__ out) {
    const int bid = blockIdx.x, t = threadIdx.x;
    __shared__ float red[4];
    if (bid < BATCH) {
        if (bid == 0 && t == 0) out[0] = 0.f;
        int i = bid;
        float2 v = *(const float2*)&x[(size_t)i * FDIM + 2 * t];
        xq[pdst4(i, 2 * t)] = (unsigned char)(fp4e(v.x) | (fp4e(v.y) << 4));
        float s = v.x * v.x + v.y * v.y;
#pragma unroll
        for (int m = 1; m < 64; m <<= 1) s += __shfl_xor(s, m);
        if ((t & 63) == 0) red[t >> 6] = s;
        __syncthreads();
        if (t == 0) xnorm[i] = red[0] + red[1] + red[2] + red[3];
        return;
    }
    int j = bid - BATCH;
    if (j >= NCLS) {  // padding rows: zero fp4, huge norm -> rcp(1+d) ~ 1e-30 (self-masking)
        cq[pdst4(j, 2 * t)] = 0;
        if (t == 0) cnorm[j] = 1e30f;
        return;
    }
    __shared__ int nmatch;
    __shared__ int idxs[MAXL];
    if (t == 0) nmatch = 0;
    __syncthreads();
    {   // vectorized label scan: 4 independent int4 loads (one round-trip, not 16)
        const int4* l4 = (const int4*)labels;
        int4 a0 = l4[t], a1 = l4[t + 256], a2 = l4[t + 512], a3 = l4[t + 768];
#define CHK(V, B) { \
        if (V.x == j) { int p = atomicAdd(&nmatch, 1); if (p < MAXL) idxs[p] = (B); } \
        if (V.y == j) { int p = atomicAdd(&nmatch, 1); if (p < MAXL) idxs[p] = (B) + 1; } \
        if (V.z == j) { int p = atomicAdd(&nmatch, 1); if (p < MAXL) idxs[p] = (B) + 2; } \
        if (V.w == j) { int p = atomicAdd(&nmatch, 1); if (p < MAXL) idxs[p] = (B) + 3; } }
        CHK(a0, 4 * t) CHK(a1, 4 * (t + 256)) CHK(a2, 4 * (t + 512)) CHK(a3, 4 * (t + 768))
#undef CHK
    }
    __syncthreads();
    int cfull = nmatch;
    int c = cfull > MAXL ? MAXL : cfull;
    if (t == 0 && c > 1) {  // sort tiny list -> deterministic fp add order
        for (int a = 1; a < c; ++a) {
            int v = idxs[a]; int b = a - 1;
            while (b >= 0 && idxs[b] > v) { idxs[b + 1] = idxs[b]; --b; }
            idxs[b + 1] = v;
        }
    }
    __syncthreads();
    float cf  = (float)cfull;
    float lr0 = lr[0];
    float inv = 1.f / (1.f + cf);
    float c0 = centers[(size_t)j * FDIM + 2 * t];
    float c1 = centers[(size_t)j * FDIM + 2 * t + 1];
    float sx0 = 0.f, sx1 = 0.f;
    for (int q = 0; q < c; ++q) {
        const float* xr = &x[(size_t)idxs[q] * FDIM + 2 * t];
        sx0 += xr[0]; sx1 += xr[1];
    }
    float n0 = c0 - lr0 * (cf * c0 - sx0) * inv;
    float n1 = c1 - lr0 * (cf * c1 - sx1) * inv;
    cq[pdst4(j, 2 * t)] = (unsigned char)(fp4e(n0) | (fp4e(n1) << 4));
    float cn2 = n0 * n0 + n1 * n1;
#pragma unroll
    for (int m = 1; m < 64; m <<= 1) cn2 += __shfl_xor(cn2, m);
    if ((t & 63) == 0) red[t >> 6] = cn2;
    __syncthreads();
    if (t == 0) cnorm[j] = red[0] + red[1] + red[2] + red[3];
}

// ---------------- pairwise: N-streaming MX-fp4. 512 blocks (2/CU), A-panel resident in
// REGISTERS (whole K=512), B streamed as 10 x 64-col half-panels, 2-buf counted vmcnt. ----------------
__global__ void __launch_bounds__(256, 2)
pairwise(const unsigned char* __restrict__ xq, const unsigned char* __restrict__ cq,
         const float* __restrict__ xnorm, const float* __restrict__ cnorm,
         const int* __restrict__ labels, float* __restrict__ row_part) {
    __shared__ unsigned char Als[32768];        // A panel: 128 rows x K=512 fp4
    __shared__ unsigned char Bls[2][16384];     // B half-panel double buffer: 64 rows x K=512
    __shared__ unsigned char Cnls[4096];        // cnorm[g*640 .. +640] (+ slack)
    const int tid = threadIdx.x;
    const int w = tid >> 6, lane = tid & 63;
    const int lr16 = lane & 15, lhi = lane >> 4;
    // XCD swizzle: 512 = 8 XCD * 64 (2 g-groups x 32 bx per XCD)
    const int bid = blockIdx.x;
    const int swz = (bid & 7) * 64 + (bid >> 3);
    const int bx = swz & 31, g = swz >> 5;       // bx: m-tile, g: n-group of 640 cols
    const int m_blk = bx * 128;
    const int mq = (w >> 1) * 64, nqh = (w & 1) * 32;

    // prologue VMEM (issued oldest-first; all retired by the first vmcnt(4)):
    float xn[4]; int lab[4];
#pragma unroll
    for (int mi = 0; mi < 4; ++mi) {
        int m_g = m_blk + mq + mi * 16 + lr16;
        xn[mi]  = xnorm[m_g];
        lab[mi] = labels[m_g];
    }
    {   // A panel (8 chunks), cnorm slice (1), B half-panel 0 (4)
        const unsigned char* gA = xq + (size_t)(m_blk >> 4) * 4096 + tid * 16;
#pragma unroll
        for (int q = 0; q < 8; ++q) gld_lds16(gA + q * 4096, &Als[q * 4096 + tid * 16]);
        gld_lds16((const char*)cnorm + (size_t)g * 2560 + tid * 16, &Cnls[tid * 16]);
        const unsigned char* gB0 = cq + (size_t)g * 40960 + tid * 16;
#pragma unroll
        for (int q = 0; q < 4; ++q) gld_lds16(gB0 + q * 4096, &Bls[0][q * 4096 + tid * 16]);
    }
    const unsigned char* gB = cq + (size_t)g * 40960 + tid * 16;   // +s*16384 per step

    ix8 afr[4][4];      // A fragments, whole K in registers: [mi][kt2], 128 VGPR
    f32x4 acc[4][2];
    float rsum[4] = {0.f, 0.f, 0.f, 0.f};

    for (int s = 0; s < 10; ++s) {
        // stage next half-panel into the buffer released at step s-1
        if (s < 9) {
            const unsigned char* gs = gB + (size_t)(s + 1) * 16384;
            unsigned char* ls = &Bls[(s + 1) & 1][0];
#pragma unroll
            for (int q = 0; q < 4; ++q) gld_lds16(gs + q * 4096, &ls[q * 4096 + tid * 16]);
            asm volatile("s_waitcnt vmcnt(4)" ::: "memory");   // B[s] (and older) done
        } else {
            asm volatile("s_waitcnt vmcnt(0)" ::: "memory");
        }
        __builtin_amdgcn_s_barrier();

        if (s == 0) {   // A-frags LDS->regs once (16 ds_read_b128, lane-linear)
#pragma unroll
            for (int mi = 0; mi < 4; ++mi)
#pragma unroll
                for (int kt2 = 0; kt2 < 4; ++kt2) {
                    ix4 lo = *(const ix4*)&Als[((mq >> 4) + mi) * 4096 + kt2 * 1024 + lane * 16];
                    afr[mi][kt2] = __builtin_shufflevector(lo, lo, 0, 1, 2, 3, 0, 1, 2, 3);
                }
        }

#pragma unroll
        for (int mi = 0; mi < 4; ++mi)
#pragma unroll
            for (int ni = 0; ni < 2; ++ni) acc[mi][ni] = (f32x4)0.f;

        const unsigned char* bb = &Bls[s & 1][0];
#pragma unroll
        for (int kt2 = 0; kt2 < 4; ++kt2) {
            ix8 bg[2];
#pragma unroll
            for (int ni = 0; ni < 2; ++ni) {
                ix4 lo = *(const ix4*)&bb[((nqh >> 4) + ni) * 4096 + kt2 * 1024 + lane * 16];
                bg[ni] = __builtin_shufflevector(lo, lo, 0, 1, 2, 3, 0, 1, 2, 3);
            }
            __builtin_amdgcn_s_setprio(1);
#pragma unroll
            for (int mi = 0; mi < 4; ++mi)
#pragma unroll
                for (int ni = 0; ni < 2; ++ni)
                    acc[mi][ni] = __builtin_amdgcn_mfma_scale_f32_16x16x128_f8f6f4(
                        bg[ni], afr[mi][kt2], acc[mi][ni], 4, 4, 0, 0x7F7F7F7F, 0, 0x7F7F7F7F);
            __builtin_amdgcn_s_setprio(0);
        }
        __builtin_amdgcn_sched_barrier(0);
        __builtin_amdgcn_s_barrier();           // release Bls[s&1] for stage at s+1

        // fold this half-panel into running row sums (swapped mfma: m on lanes).
        // cnorm from LDS (no vmcnt impact); n_g = g*640 + s*64 + nqh + ni*16 + lhi*4 + r
        const float* cnf = (const float*)&Cnls[0];
        int nb_l = s * 64 + nqh;                 // LDS-local n index base
        int nb_g = g * 640 + nb_l;               // global n base
#pragma unroll
        for (int ni = 0; ni < 2; ++ni) {
#pragma unroll
            for (int r = 0; r < 4; ++r) {
                float cn = cnf[nb_l + ni * 16 + lhi * 4 + r];
                int n_g = nb_g + ni * 16 + lhi * 4 + r;
#pragma unroll
                for (int mi = 0; mi < 4; ++mi) {
                    float d1 = 1.f + xn[mi] + cn - 2.f * acc[mi][ni][r];
                    float rc = __builtin_amdgcn_rcpf(d1);
                    rsum[mi] += (n_g != lab[mi]) ? rc : 0.f;
                }
            }
        }
    }

    // final: reduce across lhi (16,32), combine the two n-half waves via LDS, store
#pragma unroll
    for (int mi = 0; mi < 4; ++mi) {
        rsum[mi] += __shfl_xor(rsum[mi], 16);
        rsum[mi] += __shfl_xor(rsum[mi], 32);
    }
    __syncthreads();
    float* spart = (float*)&Bls[0][0];
    if ((w & 1) && lhi == 0) {                   // nqh=32 waves deposit
#pragma unroll
        for (int mi = 0; mi < 4; ++mi)
            spart[mq + mi * 16 + lr16] = rsum[mi];
    }
    __syncthreads();
    if (!(w & 1) && lhi == 0) {                  // nqh=0 waves combine + store
        float* rp = row_part + (size_t)g * BATCH + m_blk;
#pragma unroll
        for (int mi = 0; mi < 4; ++mi) {
            int ml = mq + mi * 16 + lr16;
            rp[ml] = rsum[mi] + spart[ml];
        }
    }
}

// ---------------- finalize: sum 16 parts per row, clamp, mean ----------------
__global__ void finalize(const float* __restrict__ row_part, float* __restrict__ out) {
    int i = blockIdx.x * 256 + threadIdx.x;   // 4096 rows
    float s = 0.f;
#pragma unroll
    for (int p = 0; p < 16; ++p) s += row_part[(size_t)p * BATCH + i];
    float dist = fminf(fmaxf(s, 1e-12f), 1e12f);
    float v = dist * (1.f / BATCH);
#pragma unroll
    for (int m = 1; m < 64; m <<= 1) v += __shfl_xor(v, m);
    __shared__ float red[4];
    if ((threadIdx.x & 63) == 0) red[threadIdx.x >> 6] = v;
    __syncthreads();
    if (threadIdx.x == 0) atomicAdd(out, red[0] + red[1] + red[2] + red[3]);
}

extern "C" void kernel_launch(void* const* d_in, const int* in_sizes, int n_in,
                              void* d_out, int out_size, void* d_ws, size_t ws_size,
                              hipStream_t stream) {
    const float* x       = (const float*)d_in[0];
    const int*   labels  = (const int*)d_in[1];
    const float* centers = (const float*)d_in[2];
    const float* lr      = (const float*)d_in[3];
    float* out = (float*)d_out;

    char* ws = (char*)d_ws;
    size_t off = 0;
    unsigned char* cq = (unsigned char*)(ws + off); off += (size_t)CPAD * FDIM / 2;   // 2.62 MB
    unsigned char* xq = (unsigned char*)(ws + off); off += (size_t)BATCH * FDIM / 2;  // 1.05 MB
    float* cnorm    = (float*)(ws + off); off += (size_t)CPAD * 4;                    // 40 KB
    float* xnorm    = (float*)(ws + off); off += (size_t)BATCH * 4;                   // 16 KB
    float* row_part = (float*)(ws + off); off += (size_t)16 * BATCH * 4;              // 256 KB

    prep_all<<<BATCH + CPAD, 256, 0, stream>>>(x, labels, centers, lr,
                                               xq, xnorm, cq, cnorm, out);
    pairwise<<<512, 256, 0, stream>>>(xq, cq, xnorm, cnorm, labels, row_part);
    finalize<<<BATCH / 256, 256, 0, stream>>>(row_part, out);
}